// Round 1
// baseline (556.704 us; speedup 1.0000x reference)
//
#include <hip/hip_runtime.h>
#include <math.h>

#define B_ 32
#define C_ 256
#define D_ 128
#define H_ 56
#define W_ 56
#define N_ 3136

// ---------------------------------------------------------------------------
// K1: qk[b,o,n] = elu( sum_c W[o,c]*x[b,c,n] + bias[o] ) + 1
// GEMM M=256(o) N=3136(n) K=256(c), 64x64 tile, 4x4 micro-tile.
// ---------------------------------------------------------------------------
__global__ __launch_bounds__(256) void k1_qk(
    const float* __restrict__ x, const float* __restrict__ w,
    const float* __restrict__ bias, float* __restrict__ qk)
{
  __shared__ float Ws[16][68];   // [k][o], pad 68 (272B rows, 16B aligned)
  __shared__ float Xs[16][64];   // [k][n]
  const int tid = threadIdx.x;
  const int tx = tid & 15, ty = tid >> 4;
  const int n0 = blockIdx.x * 64;
  const int o0 = blockIdx.y * 64;
  const int b  = blockIdx.z;
  const float* xb = x + (size_t)b * C_ * N_;
  float acc[4][4] = {};
  const int lr = tid >> 2, lq = tid & 3;   // W tile: row o0+lr, float4 col lq
  const int xr = tid >> 4, xc = tid & 15;  // X tile: row k0+xr, float4 col xc

  for (int k0 = 0; k0 < C_; k0 += 16) {
    float4 wv = *(const float4*)(w  + (size_t)(o0 + lr) * C_ + k0 + lq * 4);
    float4 xv = *(const float4*)(xb + (size_t)(k0 + xr) * N_ + n0 + xc * 4);
    __syncthreads();
    Ws[lq*4+0][lr] = wv.x; Ws[lq*4+1][lr] = wv.y;
    Ws[lq*4+2][lr] = wv.z; Ws[lq*4+3][lr] = wv.w;
    *(float4*)(&Xs[xr][xc*4]) = xv;
    __syncthreads();
#pragma unroll
    for (int kk = 0; kk < 16; ++kk) {
      float4 a  = *(const float4*)(&Ws[kk][ty*4]);
      float4 bv = *(const float4*)(&Xs[kk][tx*4]);
      float av[4] = {a.x, a.y, a.z, a.w};
      float bb[4] = {bv.x, bv.y, bv.z, bv.w};
#pragma unroll
      for (int i = 0; i < 4; ++i)
#pragma unroll
        for (int j = 0; j < 4; ++j)
          acc[i][j] += av[i] * bb[j];
    }
  }

#pragma unroll
  for (int i = 0; i < 4; ++i) {
    const int o = o0 + ty*4 + i;
    const float bval = bias[o];
    float4 r;
    float v;
    v = acc[i][0] + bval; r.x = v > 0.f ? v + 1.f : expf(v);
    v = acc[i][1] + bval; r.y = v > 0.f ? v + 1.f : expf(v);
    v = acc[i][2] + bval; r.z = v > 0.f ? v + 1.f : expf(v);
    v = acc[i][3] + bval; r.w = v > 0.f ? v + 1.f : expf(v);
    *(float4*)(qk + ((size_t)b*C_ + o)*N_ + n0 + tx*4) = r;
  }
}

// ---------------------------------------------------------------------------
// K2: kv[b,d,c] = (1/N) * sum_n k[b,d,n] * x[b,c,n]   (k = qk channels 128..255)
// GEMM-NT M=128(d) N=256(c) K=3136(n), BK=32.
// ---------------------------------------------------------------------------
__global__ __launch_bounds__(256) void k2_kv(
    const float* __restrict__ qk, const float* __restrict__ x,
    float* __restrict__ kv)
{
  __shared__ float As[32][68];   // [n-k][d]
  __shared__ float Bs[32][68];   // [n-k][c]
  const int tid = threadIdx.x;
  const int tx = tid & 15, ty = tid >> 4;
  const int c0 = blockIdx.x * 64;
  const int d0 = blockIdx.y * 64;
  const int b  = blockIdx.z;
  const float* ka = qk + ((size_t)b * C_ + 128 + d0) * N_;
  const float* xb = x  + ((size_t)b * C_ + c0) * N_;
  float acc[4][4] = {};
  const int r0 = tid >> 3, q0 = tid & 7;  // rows 0..31, float4 col 0..7
  const int r1 = r0 + 32;                 // rows 32..63

  for (int n0 = 0; n0 < N_; n0 += 32) {
    float4 a0 = *(const float4*)(ka + (size_t)r0 * N_ + n0 + q0*4);
    float4 a1 = *(const float4*)(ka + (size_t)r1 * N_ + n0 + q0*4);
    float4 b0 = *(const float4*)(xb + (size_t)r0 * N_ + n0 + q0*4);
    float4 b1 = *(const float4*)(xb + (size_t)r1 * N_ + n0 + q0*4);
    __syncthreads();
    As[q0*4+0][r0]=a0.x; As[q0*4+1][r0]=a0.y; As[q0*4+2][r0]=a0.z; As[q0*4+3][r0]=a0.w;
    As[q0*4+0][r1]=a1.x; As[q0*4+1][r1]=a1.y; As[q0*4+2][r1]=a1.z; As[q0*4+3][r1]=a1.w;
    Bs[q0*4+0][r0]=b0.x; Bs[q0*4+1][r0]=b0.y; Bs[q0*4+2][r0]=b0.z; Bs[q0*4+3][r0]=b0.w;
    Bs[q0*4+0][r1]=b1.x; Bs[q0*4+1][r1]=b1.y; Bs[q0*4+2][r1]=b1.z; Bs[q0*4+3][r1]=b1.w;
    __syncthreads();
#pragma unroll
    for (int kk = 0; kk < 32; ++kk) {
      float4 a  = *(const float4*)(&As[kk][ty*4]);
      float4 bv = *(const float4*)(&Bs[kk][tx*4]);
      float av[4] = {a.x, a.y, a.z, a.w};
      float bb[4] = {bv.x, bv.y, bv.z, bv.w};
#pragma unroll
      for (int i = 0; i < 4; ++i)
#pragma unroll
        for (int j = 0; j < 4; ++j)
          acc[i][j] += av[i] * bb[j];
    }
  }

  const float sc = 1.0f / (float)N_;
#pragma unroll
  for (int i = 0; i < 4; ++i) {
    float4 r;
    r.x = acc[i][0]*sc; r.y = acc[i][1]*sc; r.z = acc[i][2]*sc; r.w = acc[i][3]*sc;
    *(float4*)(kv + ((size_t)b*D_ + d0+ty*4+i)*C_ + c0 + tx*4) = r;
  }
}

// ---------------------------------------------------------------------------
// K2b: kmean[b,d] = (1/N) sum_n k[b,d,n]
// ---------------------------------------------------------------------------
__global__ __launch_bounds__(256) void k2b_kmean(
    const float* __restrict__ qk, float* __restrict__ km)
{
  const int row = blockIdx.x;            // 0..B*D-1
  const int b = row >> 7, d = row & 127;
  const float* kp = qk + ((size_t)b*C_ + 128 + d) * N_;
  float s = 0.f;
  for (int i = threadIdx.x; i < N_; i += 256) s += kp[i];
#pragma unroll
  for (int off = 32; off; off >>= 1) s += __shfl_down(s, off, 64);
  __shared__ float red[4];
  if ((threadIdx.x & 63) == 0) red[threadIdx.x >> 6] = s;
  __syncthreads();
  if (threadIdx.x == 0)
    km[row] = (red[0] + red[1] + red[2] + red[3]) / (float)N_;
}

// ---------------------------------------------------------------------------
// K3: out[b,c,n] = (sum_d q[b,d,n]*kv[b,d,c]) / (sum_d q[b,d,n]*km[b,d] + 1e-6)
// GEMM M=256(c) N=3136(n) K=128(d). Both operands natural [k][*] layout.
// ---------------------------------------------------------------------------
__global__ __launch_bounds__(256) void k3_attn(
    const float* __restrict__ qk, const float* __restrict__ kv,
    const float* __restrict__ km, float* __restrict__ out)
{
  __shared__ float Akv[16][64];  // [d-k][c]
  __shared__ float Bq[16][64];   // [d-k][n]
  __shared__ float kms[128];
  const int tid = threadIdx.x;
  const int tx = tid & 15, ty = tid >> 4;
  const int n0 = blockIdx.x * 64;
  const int c0 = blockIdx.y * 64;
  const int b  = blockIdx.z;
  if (tid < 128) kms[tid] = km[b*D_ + tid];
  const int r = tid >> 4, q = tid & 15;
  float acc[4][4] = {};
  float den[4] = {};

  for (int k0 = 0; k0 < D_; k0 += 16) {
    float4 av = *(const float4*)(kv + ((size_t)b*D_ + k0 + r)*C_ + c0 + q*4);
    float4 qv = *(const float4*)(qk + ((size_t)b*C_ + k0 + r)*N_ + n0 + q*4);
    __syncthreads();
    *(float4*)(&Akv[r][q*4]) = av;
    *(float4*)(&Bq[r][q*4])  = qv;
    __syncthreads();
#pragma unroll
    for (int kk = 0; kk < 16; ++kk) {
      float4 a  = *(const float4*)(&Akv[kk][ty*4]);
      float4 bv = *(const float4*)(&Bq[kk][tx*4]);
      const float kmv = kms[k0 + kk];
      float av2[4] = {a.x, a.y, a.z, a.w};
      float bb[4] = {bv.x, bv.y, bv.z, bv.w};
#pragma unroll
      for (int i = 0; i < 4; ++i)
#pragma unroll
        for (int j = 0; j < 4; ++j)
          acc[i][j] += av2[i] * bb[j];
      den[0] += bb[0]*kmv; den[1] += bb[1]*kmv;
      den[2] += bb[2]*kmv; den[3] += bb[3]*kmv;
    }
  }

#pragma unroll
  for (int i = 0; i < 4; ++i) {
    float4 r4;
    r4.x = acc[i][0] / (den[0] + 1e-6f);
    r4.y = acc[i][1] / (den[1] + 1e-6f);
    r4.z = acc[i][2] / (den[2] + 1e-6f);
    r4.w = acc[i][3] / (den[3] + 1e-6f);
    *(float4*)(out + ((size_t)b*C_ + c0+ty*4+i)*N_ + n0 + tx*4) = r4;
  }
}

// ---------------------------------------------------------------------------
// K4: out[b,ch,:,:] += depthwise3x3(x)[b,ch] + pe_b[ch]
// One block per (ch,b) plane; plane staged in LDS (12.25 KB).
// ---------------------------------------------------------------------------
__global__ __launch_bounds__(256) void k4_pe(
    const float* __restrict__ x, const float* __restrict__ pw,
    const float* __restrict__ pb, float* __restrict__ out)
{
  __shared__ float xs[N_];
  const int ch = blockIdx.x, b = blockIdx.y;
  const float* xp = x + ((size_t)b*C_ + ch)*N_;
  for (int i = threadIdx.x; i < N_; i += 256) xs[i] = xp[i];
  const float* wp = pw + ch*9;
  const float w00=wp[0], w01=wp[1], w02=wp[2];
  const float w10=wp[3], w11=wp[4], w12=wp[5];
  const float w20=wp[6], w21=wp[7], w22=wp[8];
  const float bias = pb[ch];
  __syncthreads();
  float* op = out + ((size_t)b*C_ + ch)*N_;
  for (int i = threadIdx.x; i < N_; i += 256) {
    const int hh = i / W_, ww = i - hh*W_;
    float s = bias;
    if (hh > 0) {
      const float* rp = &xs[(hh-1)*W_];
      if (ww > 0)      s += w00 * rp[ww-1];
                       s += w01 * rp[ww];
      if (ww < W_-1)   s += w02 * rp[ww+1];
    }
    {
      const float* rp = &xs[hh*W_];
      if (ww > 0)      s += w10 * rp[ww-1];
                       s += w11 * rp[ww];
      if (ww < W_-1)   s += w12 * rp[ww+1];
    }
    if (hh < H_-1) {
      const float* rp = &xs[(hh+1)*W_];
      if (ww > 0)      s += w20 * rp[ww-1];
                       s += w21 * rp[ww];
      if (ww < W_-1)   s += w22 * rp[ww+1];
    }
    op[i] += s;
  }
}

extern "C" void kernel_launch(void* const* d_in, const int* in_sizes, int n_in,
                              void* d_out, int out_size, void* d_ws, size_t ws_size,
                              hipStream_t stream) {
  (void)in_sizes; (void)n_in; (void)out_size; (void)ws_size;
  const float* x   = (const float*)d_in[0];
  const float* qkw = (const float*)d_in[1];
  const float* qkb = (const float*)d_in[2];
  const float* pew = (const float*)d_in[3];
  const float* peb = (const float*)d_in[4];
  float* out = (float*)d_out;

  float* qk = (float*)d_ws;                       // B*C*N floats (~103 MB)
  float* kv = qk + (size_t)B_*C_*N_;              // B*D*C floats (~4.2 MB)
  float* km = kv + (size_t)B_*D_*C_;              // B*D floats

  k1_qk    <<<dim3(N_/64, C_/64, B_), 256, 0, stream>>>(x, qkw, qkb, qk);
  k2_kv    <<<dim3(C_/64, D_/64, B_), 256, 0, stream>>>(qk, x, kv);
  k2b_kmean<<<dim3(B_*D_),            256, 0, stream>>>(qk, km);
  k3_attn  <<<dim3(N_/64, C_/64, B_), 256, 0, stream>>>(qk, kv, km, out);
  k4_pe    <<<dim3(C_, B_),           256, 0, stream>>>(x, pew, peb, out);
}

// Round 2
// 321.137 us; speedup vs baseline: 1.7335x; 1.7335x over previous
//
#include <hip/hip_runtime.h>

#define B_ 32
#define C_ 256
#define D_ 128
#define HH 56
#define WW 56
#define N_ 3136
#define KSPLIT 7
#define KRANGE 448   // n per K-split in k2: 14 steps of 32

typedef float f32x4 __attribute__((ext_vector_type(4)));
typedef short s16x8 __attribute__((ext_vector_type(8)));
typedef unsigned short u16x8 __attribute__((ext_vector_type(8)));

// Row swizzle for [R][32-bf16] LDS tiles (64B rows = 4x16B units).
// unit_phys = unit_logical ^ swz4(r): spreads 16-lane column reads to <=2-way
// bank conflicts (free per m136). Involution => same XOR on write & read.
__device__ __forceinline__ int swz4(int r){
  return (r & 3) ^ (((r >> 2) & 1) << 1) ^ ((r >> 3) & 1);
}
__device__ __forceinline__ unsigned short f2bf(float f){
  unsigned u = __float_as_uint(f);
  u += 0x7fffu + ((u >> 16) & 1u);           // RNE
  return (unsigned short)(u >> 16);
}
__device__ __forceinline__ float bf2f(unsigned short h){
  return __uint_as_float(((unsigned)h) << 16);
}
__device__ __forceinline__ float elu1(float v){
  return v > 0.f ? v + 1.f : __expf(v);      // elu(v)+1
}

// Stage a [R rows][32 bf16] tile from bf16 global (row pitch ld elements)
// into swizzled LDS via global_load_lds (dest = wave-uniform base + lane*16;
// swizzle applied by pre-swizzling the per-lane GLOBAL source unit, m173).
template<int R>
__device__ __forceinline__ void stage_glds(const unsigned short* gp, int ld, char* lds){
  const int tid = threadIdx.x;
  const int wid = tid >> 6;
#pragma unroll
  for (int q = 0; q < R/64; ++q){
    const int slot = q*256 + tid;            // = r*4 + unit
    const int r = slot >> 2, gi = slot & 3;
    const int u = gi ^ swz4(r);
    const unsigned short* ga = gp + r*ld + u*8;
    char* lb = lds + (q*256 + wid*64)*16;    // wave-uniform LDS base
    __builtin_amdgcn_global_load_lds(
        (__attribute__((address_space(1))) void*)ga,
        (__attribute__((address_space(3))) void*)lb, 16, 0, 0);
  }
}

// MFMA fragment read: logical 16B unit g of row r, swizzle-corrected.
__device__ __forceinline__ s16x8 ldsfrag(const char* lds, int r, int g){
  return *(const s16x8*)(lds + r*64 + ((g ^ swz4(r)) << 4));
}

// ---------------------------------------------------------------------------
// K1: qk = elu(W.x + b)+1.  MFMA GEMM M=256(o) x N=3136(n) x K=256(c).
// BM=128, BN=64, BK=32. Block y=0 -> q half, stored transposed qt[b][n][d];
// y=1 -> k half, stored kbuf[b][d][n].
// ---------------------------------------------------------------------------
__global__ __launch_bounds__(256) void k1_qk(
    const float* __restrict__ x, const float* __restrict__ w,
    const float* __restrict__ bias,
    unsigned short* __restrict__ kbuf, unsigned short* __restrict__ qt)
{
  __shared__ __align__(16) char Al[128*64];  // [128 o][32 c] bf16, swizzled
  __shared__ __align__(16) char Bl[64*64];   // [64 n][32 c]  bf16, swizzled
  const int tid = threadIdx.x, lane = tid & 63, wid = tid >> 6;
  const int n0 = blockIdx.x * 64;
  const int o0 = blockIdx.y * 128;
  const int b  = blockIdx.z;
  const float* xb = x + (size_t)b*C_*N_;
  const int wo = (wid >> 1)*64, wn = (wid & 1)*32;
  f32x4 acc[4][2] = {};

  for (int k0 = 0; k0 < C_; k0 += 32){
    __syncthreads();
    // stage A: W[o][c] fp32 -> bf16 (straight copy layout)
#pragma unroll
    for (int q = 0; q < 4; ++q){
      int idx = q*256 + tid;
      int r = idx >> 3, c4 = (idx & 7)*4;
      float4 v = *(const float4*)(w + (o0 + r)*C_ + k0 + c4);
      ushort4 hv = {f2bf(v.x), f2bf(v.y), f2bf(v.z), f2bf(v.w)};
      *(ushort4*)(Al + r*64 + ((c4*2) ^ (swz4(r) << 4))) = hv;
    }
    // stage B: x[c][n] fp32 -> Bl[n][c] bf16 (transpose scatter, 2B writes)
#pragma unroll
    for (int q = 0; q < 2; ++q){
      int idx = q*256 + tid;
      int cc = idx >> 4, nn = (idx & 15)*4;
      float4 v = *(const float4*)(xb + (size_t)(k0 + cc)*N_ + n0 + nn);
      float vv[4] = {v.x, v.y, v.z, v.w};
#pragma unroll
      for (int i = 0; i < 4; ++i){
        int r = nn + i;
        *(unsigned short*)(Bl + r*64 + ((cc*2) ^ (swz4(r) << 4))) = f2bf(vv[i]);
      }
    }
    __syncthreads();
    s16x8 af[4], bfv[2];
#pragma unroll
    for (int m = 0; m < 4; ++m)  af[m]  = ldsfrag(Al, wo + m*16 + (lane & 15), lane >> 4);
#pragma unroll
    for (int nf = 0; nf < 2; ++nf) bfv[nf] = ldsfrag(Bl, wn + nf*16 + (lane & 15), lane >> 4);
#pragma unroll
    for (int m = 0; m < 4; ++m)
#pragma unroll
      for (int nf = 0; nf < 2; ++nf)
        acc[m][nf] = __builtin_amdgcn_mfma_f32_16x16x32_bf16(af[m], bfv[nf], acc[m][nf], 0, 0, 0);
  }

  const int col = lane & 15, rg = lane >> 4;
  if (o0 == 0){
    // q half -> qt[b][n][d]; regs j are consecutive d -> 8B packed stores
#pragma unroll
    for (int m = 0; m < 4; ++m){
      const int db = wo + m*16 + rg*4;
      const float b0 = bias[db], b1 = bias[db+1], b2 = bias[db+2], b3 = bias[db+3];
#pragma unroll
      for (int nf = 0; nf < 2; ++nf){
        const int n = n0 + wn + nf*16 + col;
        f32x4 a = acc[m][nf];
        ushort4 hv = {f2bf(elu1(a[0]+b0)), f2bf(elu1(a[1]+b1)),
                      f2bf(elu1(a[2]+b2)), f2bf(elu1(a[3]+b3))};
        *(ushort4*)(qt + ((size_t)b*N_ + n)*D_ + db) = hv;
      }
    }
  } else {
    // k half -> kbuf[b][d][n]
#pragma unroll
    for (int m = 0; m < 4; ++m)
#pragma unroll
      for (int j = 0; j < 4; ++j){
        const int d = wo + m*16 + rg*4 + j;
        const float bb = bias[128 + d];
#pragma unroll
        for (int nf = 0; nf < 2; ++nf){
          const int n = n0 + wn + nf*16 + col;
          kbuf[((size_t)b*D_ + d)*N_ + n] = f2bf(elu1(acc[m][nf][j] + bb));
        }
      }
  }
}

// ---------------------------------------------------------------------------
// K2: kv_raw[d][c] partials = sum_n k[d][n]*x[c][n] over a K-split range.
// M=128(d) x N=64(c-tile) x K=448(n). Fuses kmean partial (c-tile 0 blocks).
// ---------------------------------------------------------------------------
__global__ __launch_bounds__(256) void k2_kv(
    const unsigned short* __restrict__ kbuf, const float* __restrict__ x,
    unsigned short* __restrict__ kvp, float* __restrict__ kmp)
{
  __shared__ __align__(16) char Al[128*64];  // [128 d][32 n]
  __shared__ __align__(16) char Bl[64*64];   // [64 c][32 n]
  const int tid = threadIdx.x, lane = tid & 63, wid = tid >> 6;
  const int c0 = blockIdx.x * 64;
  const int ks = blockIdx.y;
  const int b  = blockIdx.z;
  const unsigned short* kb = kbuf + (size_t)b*D_*N_ + ks*KRANGE;
  const float* xb = x + ((size_t)b*C_ + c0)*N_ + ks*KRANGE;
  const int wd = (wid >> 1)*64, wc = (wid & 1)*32;
  f32x4 acc[4][2] = {};
  float kms = 0.f;
  const bool do_km = (c0 == 0);

  for (int t = 0; t < KRANGE/32; ++t){
    __syncthreads();
    stage_glds<128>(kb + t*32, N_, Al);
#pragma unroll
    for (int q = 0; q < 2; ++q){
      int idx = q*256 + tid;
      int cc = idx >> 3, n4 = (idx & 7)*4;
      float4 v = *(const float4*)(xb + (size_t)cc*N_ + t*32 + n4);
      ushort4 hv = {f2bf(v.x), f2bf(v.y), f2bf(v.z), f2bf(v.w)};
      *(ushort4*)(Bl + cc*64 + ((n4*2) ^ (swz4(cc) << 4))) = hv;
    }
    __syncthreads();
    s16x8 af[4], bfv[2];
#pragma unroll
    for (int m = 0; m < 4; ++m)  af[m]  = ldsfrag(Al, wd + m*16 + (lane & 15), lane >> 4);
#pragma unroll
    for (int cf = 0; cf < 2; ++cf) bfv[cf] = ldsfrag(Bl, wc + cf*16 + (lane & 15), lane >> 4);
#pragma unroll
    for (int m = 0; m < 4; ++m)
#pragma unroll
      for (int cf = 0; cf < 2; ++cf)
        acc[m][cf] = __builtin_amdgcn_mfma_f32_16x16x32_bf16(af[m], bfv[cf], acc[m][cf], 0, 0, 0);
    if (do_km){
      const int dr = tid >> 1, half = tid & 1;
      const char* base = Al + dr*64;
      const int s = swz4(dr);
      uint4 u0 = *(const uint4*)(base + (((half*2 + 0) ^ s) << 4));
      uint4 u1 = *(const uint4*)(base + (((half*2 + 1) ^ s) << 4));
      const unsigned ua[8] = {u0.x,u0.y,u0.z,u0.w,u1.x,u1.y,u1.z,u1.w};
#pragma unroll
      for (int i = 0; i < 8; ++i){
        kms += bf2f((unsigned short)(ua[i] & 0xffffu));
        kms += bf2f((unsigned short)(ua[i] >> 16));
      }
    }
  }

  if (do_km){
    kms += __shfl_xor(kms, 1);
    if ((tid & 1) == 0) kmp[((size_t)b*KSPLIT + ks)*D_ + (tid >> 1)] = kms;
  }
  const int col = lane & 15, rg = lane >> 4;
#pragma unroll
  for (int m = 0; m < 4; ++m)
#pragma unroll
    for (int j = 0; j < 4; ++j){
      const int d = wd + m*16 + rg*4 + j;
#pragma unroll
      for (int cf = 0; cf < 2; ++cf){
        const int c = c0 + wc + cf*16 + col;
        kvp[(((size_t)b*KSPLIT + ks)*D_ + d)*C_ + c] = f2bf(acc[m][cf][j]);
      }
    }
}

// ---------------------------------------------------------------------------
// KR: sum K-split partials, scale 1/N, write transposed kvt[b][c][d] bf16;
// also reduce kmean partials -> km[b][d] fp32.
// ---------------------------------------------------------------------------
__global__ __launch_bounds__(256) void kr_reduce(
    const unsigned short* __restrict__ kvp, const float* __restrict__ kmp,
    unsigned short* __restrict__ kvt, float* __restrict__ km)
{
  __shared__ float T[64][65];
  const int tid = threadIdx.x;
  const int ct = blockIdx.x, dt = blockIdx.y, b = blockIdx.z;
  const int d0 = dt*64, c0 = ct*64;
  const int r = tid >> 2, cq = (tid & 3)*16;
  float v[16] = {};
  for (int j = 0; j < KSPLIT; ++j){
    const unsigned short* p = kvp + (((size_t)b*KSPLIT + j)*D_ + d0 + r)*C_ + c0 + cq;
#pragma unroll
    for (int i = 0; i < 16; ++i) v[i] += bf2f(p[i]);
  }
  const float sc = 1.0f/(float)N_;
#pragma unroll
  for (int i = 0; i < 16; ++i) T[r][cq + i] = v[i]*sc;
  __syncthreads();
  u16x8 h0, h1;
#pragma unroll
  for (int i = 0; i < 8; ++i) h0[i] = f2bf(T[cq + i][r]);
#pragma unroll
  for (int i = 0; i < 8; ++i) h1[i] = f2bf(T[cq + 8 + i][r]);
  unsigned short* o = kvt + ((size_t)b*C_ + c0 + r)*D_ + d0 + cq;
  *(u16x8*)o = h0;
  *(u16x8*)(o + 8) = h1;
  if (ct == 0 && dt == 0 && tid < D_){
    float s = 0.f;
    for (int j = 0; j < KSPLIT; ++j) s += kmp[((size_t)b*KSPLIT + j)*D_ + tid];
    km[b*D_ + tid] = s*sc;
  }
}

// ---------------------------------------------------------------------------
// K3: out[c][n] = (sum_d kvt[c][d]*qt[n][d]) / (q.km + 1e-6) + dwconv3x3 + pe_b
// M=128(c) x N=64(n) x K=128(d). den from staged B tile; conv fused epilogue.
// ---------------------------------------------------------------------------
__global__ __launch_bounds__(256) void k3_out(
    const unsigned short* __restrict__ qt, const unsigned short* __restrict__ kvt,
    const float* __restrict__ km, const float* __restrict__ x,
    const float* __restrict__ pw, const float* __restrict__ pb,
    float* __restrict__ out)
{
  __shared__ __align__(16) char Al[128*64];  // [128 c][32 d]
  __shared__ __align__(16) char Bl[64*64];   // [64 n][32 d]
  __shared__ float kms[128];
  __shared__ float dens[64];
  const int tid = threadIdx.x, lane = tid & 63, wid = tid >> 6;
  const int n0 = blockIdx.x * 64;
  const int c0 = blockIdx.y * 128;
  const int b  = blockIdx.z;
  if (tid < 128) kms[tid] = km[b*D_ + tid];
  const unsigned short* kvb = kvt + ((size_t)b*C_ + c0)*D_;
  const unsigned short* qtb = qt + ((size_t)b*N_ + n0)*D_;
  const int wc = (wid >> 1)*64, wn = (wid & 1)*32;
  f32x4 acc[4][2] = {};
  float den = 0.f;

  for (int k0 = 0; k0 < D_; k0 += 32){
    __syncthreads();
    stage_glds<128>(kvb + k0, D_, Al);
    stage_glds<64>(qtb + k0, D_, Bl);
    __syncthreads();
    s16x8 af[4], bfv[2];
#pragma unroll
    for (int m = 0; m < 4; ++m)  af[m]  = ldsfrag(Al, wc + m*16 + (lane & 15), lane >> 4);
#pragma unroll
    for (int nf = 0; nf < 2; ++nf) bfv[nf] = ldsfrag(Bl, wn + nf*16 + (lane & 15), lane >> 4);
#pragma unroll
    for (int m = 0; m < 4; ++m)
#pragma unroll
      for (int nf = 0; nf < 2; ++nf)
        acc[m][nf] = __builtin_amdgcn_mfma_f32_16x16x32_bf16(af[m], bfv[nf], acc[m][nf], 0, 0, 0);
    {
      // den partial: q[n][d-slice] . km[d-slice]
      const int nr = tid >> 2, g = tid & 3;
      uint4 u = *(const uint4*)(Bl + nr*64 + ((g ^ swz4(nr)) << 4));
      const float* kp = kms + k0 + g*8;
      const unsigned ua[4] = {u.x, u.y, u.z, u.w};
#pragma unroll
      for (int i = 0; i < 4; ++i){
        den += bf2f((unsigned short)(ua[i] & 0xffffu)) * kp[i*2];
        den += bf2f((unsigned short)(ua[i] >> 16))     * kp[i*2 + 1];
      }
    }
  }
  den += __shfl_xor(den, 1);
  den += __shfl_xor(den, 2);
  if ((tid & 3) == 0) dens[tid >> 2] = den;
  __syncthreads();

  const int col = lane & 15, rg = lane >> 4;
  const float* xb = x + (size_t)b*C_*N_;
  float* ob = out + (size_t)b*C_*N_;
#pragma unroll
  for (int nf = 0; nf < 2; ++nf){
    const int nn = wn + nf*16 + col;
    const int n = n0 + nn;
    const float rdv = 1.0f / (dens[nn] + 1e-6f);
    const int hh = n / WW, wcol = n - hh*WW;
    const bool hm = hh > 0, hp = hh < HH-1, wm = wcol > 0, wp2 = wcol < WW-1;
#pragma unroll
    for (int m = 0; m < 4; ++m)
#pragma unroll
      for (int j = 0; j < 4; ++j){
        const int c = c0 + wc + m*16 + rg*4 + j;
        const float* w9 = pw + c*9;
        const float* xp = xb + (size_t)c*N_ + n;
        float s = pb[c];
        if (hm){
          if (wm)  s += w9[0]*xp[-WW-1];
                   s += w9[1]*xp[-WW];
          if (wp2) s += w9[2]*xp[-WW+1];
        }
        if (wm)  s += w9[3]*xp[-1];
                 s += w9[4]*xp[0];
        if (wp2) s += w9[5]*xp[1];
        if (hp){
          if (wm)  s += w9[6]*xp[WW-1];
                   s += w9[7]*xp[WW];
          if (wp2) s += w9[8]*xp[WW+1];
        }
        ob[(size_t)c*N_ + n] = acc[m][nf][j]*rdv + s;
      }
  }
}

extern "C" void kernel_launch(void* const* d_in, const int* in_sizes, int n_in,
                              void* d_out, int out_size, void* d_ws, size_t ws_size,
                              hipStream_t stream) {
  (void)in_sizes; (void)n_in; (void)out_size; (void)ws_size;
  const float* x   = (const float*)d_in[0];
  const float* qkw = (const float*)d_in[1];
  const float* qkb = (const float*)d_in[2];
  const float* pew = (const float*)d_in[3];
  const float* peb = (const float*)d_in[4];
  float* out = (float*)d_out;

  // ws layout (bytes, total ~68.3 MB):
  unsigned short* kbuf = (unsigned short*)d_ws;                 // [B][128][N] bf16
  unsigned short* qt   = kbuf + (size_t)B_*D_*N_;               // [B][N][128] bf16
  unsigned short* kvp  = qt   + (size_t)B_*N_*D_;               // [B][7][128][256] bf16
  float* kmp = (float*)(kvp + (size_t)B_*KSPLIT*D_*C_);         // [B][7][128] f32
  unsigned short* kvt  = (unsigned short*)(kmp + (size_t)B_*KSPLIT*D_); // [B][256][128] bf16
  float* km  = (float*)(kvt + (size_t)B_*C_*D_);                // [B][128] f32

  k1_qk    <<<dim3(N_/64, 2, B_),      256, 0, stream>>>(x, qkw, qkb, kbuf, qt);
  k2_kv    <<<dim3(C_/64, KSPLIT, B_), 256, 0, stream>>>(kbuf, x, kvp, kmp);
  kr_reduce<<<dim3(4, 2, B_),          256, 0, stream>>>(kvp, kmp, kvt, km);
  k3_out   <<<dim3(N_/64, 2, B_),      256, 0, stream>>>(qt, kvt, km, x, pew, peb, out);
}

// Round 3
// 180.975 us; speedup vs baseline: 3.0761x; 1.7745x over previous
//
#include <hip/hip_runtime.h>

#define B_ 32
#define C_ 256
#define D_ 128
#define HH 56
#define WW 56
#define N_ 3136
#define KSPLIT 14
#define KRANGE 224   // n per K-split in k2: 7 steps of 32

typedef float f32x4 __attribute__((ext_vector_type(4)));
typedef short s16x8 __attribute__((ext_vector_type(8)));
typedef unsigned short u16x8 __attribute__((ext_vector_type(8)));

// Row swizzle for [R][32-bf16] LDS tiles (64B rows = 4x16B units).
__device__ __forceinline__ int swz4(int r){
  return (r & 3) ^ (((r >> 2) & 1) << 1) ^ ((r >> 3) & 1);
}
__device__ __forceinline__ unsigned short f2bf(float f){
  unsigned u = __float_as_uint(f);
  u += 0x7fffu + ((u >> 16) & 1u);           // RNE
  return (unsigned short)(u >> 16);
}
__device__ __forceinline__ float bf2f(unsigned short h){
  return __uint_as_float(((unsigned)h) << 16);
}
__device__ __forceinline__ float elu1(float v){
  return v > 0.f ? v + 1.f : __expf(v);      // elu(v)+1
}

// Stage [R rows][32 bf16] from bf16 global (pitch ld) into swizzled LDS via
// global_load_lds: dest is lane-linear, swizzle pre-applied on global source.
template<int R>
__device__ __forceinline__ void stage_glds(const unsigned short* gp, int ld, char* lds){
  const int tid = threadIdx.x;
  const int wid = tid >> 6;
#pragma unroll
  for (int q = 0; q < R/64; ++q){
    const int slot = q*256 + tid;            // = r*4 + unit
    const int r = slot >> 2, gi = slot & 3;
    const int u = gi ^ swz4(r);
    const unsigned short* ga = gp + r*ld + u*8;
    char* lb = lds + (q*256 + wid*64)*16;    // wave-uniform LDS base
    __builtin_amdgcn_global_load_lds(
        (__attribute__((address_space(1))) void*)ga,
        (__attribute__((address_space(3))) void*)lb, 16, 0, 0);
  }
}

__device__ __forceinline__ s16x8 ldsfrag(const char* lds, int r, int g){
  return *(const s16x8*)(lds + r*64 + ((g ^ swz4(r)) << 4));
}

// ---------------------------------------------------------------------------
// K1: qk = elu(W.x + b)+1.  MFMA GEMM M=256(o) x BN=64(n) x K=256(c), BM=256
// (one block stages x once for BOTH q and k halves). Waves 0-1 -> q half
// stored transposed qt[b][n][d]; waves 2-3 -> k half stored kbuf[b][d][n].
// ---------------------------------------------------------------------------
__global__ __launch_bounds__(256) void k1_qk(
    const float* __restrict__ x, const float* __restrict__ w,
    const float* __restrict__ bias,
    unsigned short* __restrict__ kbuf, unsigned short* __restrict__ qt)
{
  __shared__ __align__(16) char Al[256*64];  // [256 o][32 c] bf16, swizzled
  __shared__ __align__(16) char Bl[64*64];   // [64 n][32 c]  bf16, swizzled
  const int tid = threadIdx.x, lane = tid & 63, wid = tid >> 6;
  const int n0 = blockIdx.x * 64;
  const int b  = blockIdx.y;
  const float* xb = x + (size_t)b*C_*N_;
  const int wo = wid*64;
  f32x4 acc[4][4] = {};

  for (int k0 = 0; k0 < C_; k0 += 32){
    __syncthreads();
    // stage A: W[o][c] fp32 -> bf16
#pragma unroll
    for (int q = 0; q < 8; ++q){
      int idx = q*256 + tid;
      int r = idx >> 3, c4 = (idx & 7)*4;
      float4 v = *(const float4*)(w + (size_t)r*C_ + k0 + c4);
      ushort4 hv = {f2bf(v.x), f2bf(v.y), f2bf(v.z), f2bf(v.w)};
      *(ushort4*)(Al + r*64 + ((c4*2) ^ (swz4(r) << 4))) = hv;
    }
    // stage B: x[c][n] fp32 -> Bl[n][c] bf16 (transpose scatter)
#pragma unroll
    for (int q = 0; q < 2; ++q){
      int idx = q*256 + tid;
      int cc = idx >> 4, nn = (idx & 15)*4;
      float4 v = *(const float4*)(xb + (size_t)(k0 + cc)*N_ + n0 + nn);
      float vv[4] = {v.x, v.y, v.z, v.w};
#pragma unroll
      for (int i = 0; i < 4; ++i){
        int r = nn + i;
        *(unsigned short*)(Bl + r*64 + ((cc*2) ^ (swz4(r) << 4))) = f2bf(vv[i]);
      }
    }
    __syncthreads();
    s16x8 af[4], bv4[4];
#pragma unroll
    for (int m = 0; m < 4; ++m)  af[m]  = ldsfrag(Al, wo + m*16 + (lane & 15), lane >> 4);
#pragma unroll
    for (int nf = 0; nf < 4; ++nf) bv4[nf] = ldsfrag(Bl, nf*16 + (lane & 15), lane >> 4);
#pragma unroll
    for (int m = 0; m < 4; ++m)
#pragma unroll
      for (int nf = 0; nf < 4; ++nf)
        acc[m][nf] = __builtin_amdgcn_mfma_f32_16x16x32_bf16(af[m], bv4[nf], acc[m][nf], 0, 0, 0);
  }

  const int col = lane & 15, rg = lane >> 4;
  if (wid < 2){
    // q half -> qt[b][n][d]
#pragma unroll
    for (int m = 0; m < 4; ++m){
      const int db = wo + m*16 + rg*4;
      const float b0 = bias[db], b1 = bias[db+1], b2 = bias[db+2], b3 = bias[db+3];
#pragma unroll
      for (int nf = 0; nf < 4; ++nf){
        const int n = n0 + nf*16 + col;
        f32x4 a = acc[m][nf];
        ushort4 hv = {f2bf(elu1(a[0]+b0)), f2bf(elu1(a[1]+b1)),
                      f2bf(elu1(a[2]+b2)), f2bf(elu1(a[3]+b3))};
        *(ushort4*)(qt + ((size_t)b*N_ + n)*D_ + db) = hv;
      }
    }
  } else {
    // k half -> kbuf[b][d][n]
#pragma unroll
    for (int m = 0; m < 4; ++m)
#pragma unroll
      for (int j = 0; j < 4; ++j){
        const int d = wo - 128 + m*16 + rg*4 + j;
        const float bb = bias[128 + d];
#pragma unroll
        for (int nf = 0; nf < 4; ++nf){
          const int n = n0 + nf*16 + col;
          kbuf[((size_t)b*D_ + d)*N_ + n] = f2bf(elu1(acc[m][nf][j] + bb));
        }
      }
  }
}

// ---------------------------------------------------------------------------
// K2: kv partials = sum_n k[d][n]*x[c][n] over K-split. M=128(d) x BN=128(c)
// x K=224(n). Fuses kmean partial (c-tile 0 blocks).
// ---------------------------------------------------------------------------
__global__ __launch_bounds__(256) void k2_kv(
    const unsigned short* __restrict__ kbuf, const float* __restrict__ x,
    unsigned short* __restrict__ kvp, float* __restrict__ kmp)
{
  __shared__ __align__(16) char Al[128*64];  // [128 d][32 n]
  __shared__ __align__(16) char Bl[128*64];  // [128 c][32 n]
  const int tid = threadIdx.x, lane = tid & 63, wid = tid >> 6;
  const int c0 = blockIdx.x * 128;
  const int ks = blockIdx.y;
  const int b  = blockIdx.z;
  const unsigned short* kb = kbuf + (size_t)b*D_*N_ + ks*KRANGE;
  const float* xb = x + ((size_t)b*C_ + c0)*N_ + ks*KRANGE;
  const int wd = (wid >> 1)*64, wc = (wid & 1)*64;
  f32x4 acc[4][4] = {};
  float kms = 0.f;
  const bool do_km = (c0 == 0);

  for (int t = 0; t < KRANGE/32; ++t){
    __syncthreads();
    stage_glds<128>(kb + t*32, N_, Al);
#pragma unroll
    for (int q = 0; q < 4; ++q){
      int idx = q*256 + tid;
      int cc = idx >> 3, n4 = (idx & 7)*4;
      float4 v = *(const float4*)(xb + (size_t)cc*N_ + t*32 + n4);
      ushort4 hv = {f2bf(v.x), f2bf(v.y), f2bf(v.z), f2bf(v.w)};
      *(ushort4*)(Bl + cc*64 + ((n4*2) ^ (swz4(cc) << 4))) = hv;
    }
    __syncthreads();
    s16x8 af[4], bv4[4];
#pragma unroll
    for (int m = 0; m < 4; ++m)  af[m]  = ldsfrag(Al, wd + m*16 + (lane & 15), lane >> 4);
#pragma unroll
    for (int cf = 0; cf < 4; ++cf) bv4[cf] = ldsfrag(Bl, wc + cf*16 + (lane & 15), lane >> 4);
#pragma unroll
    for (int m = 0; m < 4; ++m)
#pragma unroll
      for (int cf = 0; cf < 4; ++cf)
        acc[m][cf] = __builtin_amdgcn_mfma_f32_16x16x32_bf16(af[m], bv4[cf], acc[m][cf], 0, 0, 0);
    if (do_km){
      const int dr = tid >> 1, half = tid & 1;
      const char* base = Al + dr*64;
      const int s = swz4(dr);
      uint4 u0 = *(const uint4*)(base + (((half*2 + 0) ^ s) << 4));
      uint4 u1 = *(const uint4*)(base + (((half*2 + 1) ^ s) << 4));
      const unsigned ua[8] = {u0.x,u0.y,u0.z,u0.w,u1.x,u1.y,u1.z,u1.w};
#pragma unroll
      for (int i = 0; i < 8; ++i){
        kms += bf2f((unsigned short)(ua[i] & 0xffffu));
        kms += bf2f((unsigned short)(ua[i] >> 16));
      }
    }
  }

  if (do_km){
    kms += __shfl_xor(kms, 1);
    if ((tid & 1) == 0) kmp[((size_t)b*KSPLIT + ks)*D_ + (tid >> 1)] = kms;
  }
  const int col = lane & 15, rg = lane >> 4;
#pragma unroll
  for (int m = 0; m < 4; ++m)
#pragma unroll
    for (int j = 0; j < 4; ++j){
      const int d = wd + m*16 + rg*4 + j;
#pragma unroll
      for (int cf = 0; cf < 4; ++cf){
        const int c = c0 + wc + cf*16 + col;
        kvp[(((size_t)b*KSPLIT + ks)*D_ + d)*C_ + c] = f2bf(acc[m][cf][j]);
      }
    }
}

// ---------------------------------------------------------------------------
// KR: sum K-split partials, scale 1/N, write transposed kvt[b][c][d] bf16;
// reduce kmean partials -> km[b][d] fp32.
// ---------------------------------------------------------------------------
__global__ __launch_bounds__(256) void kr_reduce(
    const unsigned short* __restrict__ kvp, const float* __restrict__ kmp,
    unsigned short* __restrict__ kvt, float* __restrict__ km)
{
  __shared__ float T[64][65];
  const int tid = threadIdx.x;
  const int ct = blockIdx.x, dt = blockIdx.y, b = blockIdx.z;
  const int d0 = dt*64, c0 = ct*64;
  const int r = tid >> 2, cq = (tid & 3)*16;
  float v[16] = {};
  for (int j = 0; j < KSPLIT; ++j){
    const unsigned short* p = kvp + (((size_t)b*KSPLIT + j)*D_ + d0 + r)*C_ + c0 + cq;
#pragma unroll
    for (int i = 0; i < 16; ++i) v[i] += bf2f(p[i]);
  }
  const float sc = 1.0f/(float)N_;
#pragma unroll
  for (int i = 0; i < 16; ++i) T[r][cq + i] = v[i]*sc;
  __syncthreads();
  u16x8 h0, h1;
#pragma unroll
  for (int i = 0; i < 8; ++i) h0[i] = f2bf(T[cq + i][r]);
#pragma unroll
  for (int i = 0; i < 8; ++i) h1[i] = f2bf(T[cq + 8 + i][r]);
  unsigned short* o = kvt + ((size_t)b*C_ + c0 + r)*D_ + d0 + cq;
  *(u16x8*)o = h0;
  *(u16x8*)(o + 8) = h1;
  if (ct == 0 && dt == 0 && tid < D_){
    float s = 0.f;
    for (int j = 0; j < KSPLIT; ++j) s += kmp[((size_t)b*KSPLIT + j)*D_ + tid];
    km[b*D_ + tid] = s*sc;
  }
}

// ---------------------------------------------------------------------------
// K3: attn[c][n] = (sum_d kvt[c][d]*qt[n][d]) / (q.km + 1e-6), bf16 out.
// M=128(c) x N=64(n) x K=128(d). Epilogue packs via LDS transpose so global
// stores are 16B row segments.
// ---------------------------------------------------------------------------
__global__ __launch_bounds__(256) void k3_attn(
    const unsigned short* __restrict__ qt, const unsigned short* __restrict__ kvt,
    const float* __restrict__ km, unsigned short* __restrict__ attn)
{
  __shared__ __align__(16) char SM[128*72*2];   // 18KB: GEMM tiles, then P
  char* Al = SM;                                 // [128 c][32 d] (8KB)
  char* Bl = SM + 128*64;                        // [64 n][32 d]  (4KB)
  unsigned short* P = (unsigned short*)SM;       // [128][72] bf16 (pad 72)
  __shared__ float kms[128];
  __shared__ float dens[64];
  const int tid = threadIdx.x, lane = tid & 63, wid = tid >> 6;
  const int n0 = blockIdx.x * 64;
  const int c0 = blockIdx.y * 128;
  const int b  = blockIdx.z;
  if (tid < 128) kms[tid] = km[b*D_ + tid];
  const unsigned short* kvb = kvt + ((size_t)b*C_ + c0)*D_;
  const unsigned short* qtb = qt + ((size_t)b*N_ + n0)*D_;
  const int wc = (wid >> 1)*64, wn = (wid & 1)*32;
  f32x4 acc[4][2] = {};
  float den = 0.f;

  for (int k0 = 0; k0 < D_; k0 += 32){
    __syncthreads();
    stage_glds<128>(kvb + k0, D_, Al);
    stage_glds<64>(qtb + k0, D_, Bl);
    __syncthreads();
    s16x8 af[4], bv4[2];
#pragma unroll
    for (int m = 0; m < 4; ++m)  af[m]  = ldsfrag(Al, wc + m*16 + (lane & 15), lane >> 4);
#pragma unroll
    for (int nf = 0; nf < 2; ++nf) bv4[nf] = ldsfrag(Bl, wn + nf*16 + (lane & 15), lane >> 4);
#pragma unroll
    for (int m = 0; m < 4; ++m)
#pragma unroll
      for (int nf = 0; nf < 2; ++nf)
        acc[m][nf] = __builtin_amdgcn_mfma_f32_16x16x32_bf16(af[m], bv4[nf], acc[m][nf], 0, 0, 0);
    {
      const int nr = tid >> 2, g = tid & 3;
      uint4 u = *(const uint4*)(Bl + nr*64 + ((g ^ swz4(nr)) << 4));
      const float* kp = kms + k0 + g*8;
      const unsigned ua[4] = {u.x, u.y, u.z, u.w};
#pragma unroll
      for (int i = 0; i < 4; ++i){
        den += bf2f((unsigned short)(ua[i] & 0xffffu)) * kp[i*2];
        den += bf2f((unsigned short)(ua[i] >> 16))     * kp[i*2 + 1];
      }
    }
  }
  den += __shfl_xor(den, 1);
  den += __shfl_xor(den, 2);
  if ((tid & 3) == 0) dens[tid >> 2] = den;
  __syncthreads();   // GEMM LDS reads done + dens visible

  const int col = lane & 15, rg = lane >> 4;
  float rdv[2];
#pragma unroll
  for (int nf = 0; nf < 2; ++nf)
    rdv[nf] = 1.0f / (dens[wn + nf*16 + col] + 1e-6f);
#pragma unroll
  for (int m = 0; m < 4; ++m)
#pragma unroll
    for (int nf = 0; nf < 2; ++nf)
#pragma unroll
      for (int j = 0; j < 4; ++j)
        P[(wc + m*16 + rg*4 + j)*72 + (wn + nf*16 + col)] = f2bf(acc[m][nf][j] * rdv[nf]);
  __syncthreads();

#pragma unroll
  for (int p = 0; p < 4; ++p){
    const int c = (tid >> 3) + p*32, ch = tid & 7;
    u16x8 v = *(const u16x8*)(P + c*72 + ch*8);
    *(u16x8*)(attn + ((size_t)b*C_ + c0 + c)*N_ + n0 + ch*8) = v;
  }
}

// ---------------------------------------------------------------------------
// K4: out[b,ch,:,:] = attn + depthwise3x3(x) + pe_b. Plane per block,
// lane-consecutive-n -> conflict-free LDS, fully coalesced global.
// ---------------------------------------------------------------------------
__global__ __launch_bounds__(256) void k4_pe(
    const float* __restrict__ x, const unsigned short* __restrict__ attn,
    const float* __restrict__ pw, const float* __restrict__ pb,
    float* __restrict__ out)
{
  __shared__ float xs[N_];
  const int ch = blockIdx.x, b = blockIdx.y;
  const float* xp = x + ((size_t)b*C_ + ch)*N_;
  for (int i = threadIdx.x; i < N_/4; i += 256)
    ((float4*)xs)[i] = ((const float4*)xp)[i];
  const float* wp = pw + ch*9;
  const float w00=wp[0], w01=wp[1], w02=wp[2];
  const float w10=wp[3], w11=wp[4], w12=wp[5];
  const float w20=wp[6], w21=wp[7], w22=wp[8];
  const float bias = pb[ch];
  __syncthreads();
  const unsigned short* ap = attn + ((size_t)b*C_ + ch)*N_;
  float* op = out + ((size_t)b*C_ + ch)*N_;
  for (int i = threadIdx.x; i < N_; i += 256) {
    const int hh = i / WW, ww = i - hh*WW;
    float s = bias;
    if (hh > 0) {
      const float* rp = &xs[(hh-1)*WW];
      if (ww > 0)      s += w00 * rp[ww-1];
                       s += w01 * rp[ww];
      if (ww < WW-1)   s += w02 * rp[ww+1];
    }
    {
      const float* rp = &xs[hh*WW];
      if (ww > 0)      s += w10 * rp[ww-1];
                       s += w11 * rp[ww];
      if (ww < WW-1)   s += w12 * rp[ww+1];
    }
    if (hh < HH-1) {
      const float* rp = &xs[(hh+1)*WW];
      if (ww > 0)      s += w20 * rp[ww-1];
                       s += w21 * rp[ww];
      if (ww < WW-1)   s += w22 * rp[ww+1];
    }
    op[i] = bf2f(ap[i]) + s;
  }
}

extern "C" void kernel_launch(void* const* d_in, const int* in_sizes, int n_in,
                              void* d_out, int out_size, void* d_ws, size_t ws_size,
                              hipStream_t stream) {
  (void)in_sizes; (void)n_in; (void)out_size; (void)ws_size;
  const float* x   = (const float*)d_in[0];
  const float* qkw = (const float*)d_in[1];
  const float* qkb = (const float*)d_in[2];
  const float* pew = (const float*)d_in[3];
  const float* peb = (const float*)d_in[4];
  float* out = (float*)d_out;

  // ws layout (~104.9 MB used; attn aliases dead kvp/kmp region):
  unsigned short* kbuf = (unsigned short*)d_ws;                 // [B][128][N] bf16
  unsigned short* qt   = kbuf + (size_t)B_*D_*N_;               // [B][N][128] bf16
  unsigned short* kvt  = qt   + (size_t)B_*N_*D_;               // [B][256][128] bf16
  float* km  = (float*)(kvt + (size_t)B_*C_*D_);                // [B][128] f32
  unsigned short* kvp  = (unsigned short*)(km + (size_t)B_*D_); // [B][14][128][256] bf16
  float* kmp = (float*)(kvp + (size_t)B_*KSPLIT*D_*C_);         // [B][14][128] f32
  unsigned short* attn = kvp;  // [B][256][N] bf16 — reuse after kr_reduce

  k1_qk    <<<dim3(N_/64, B_),         256, 0, stream>>>(x, qkw, qkb, kbuf, qt);
  k2_kv    <<<dim3(C_/128, KSPLIT, B_),256, 0, stream>>>(kbuf, x, kvp, kmp);
  kr_reduce<<<dim3(4, 2, B_),          256, 0, stream>>>(kvp, kmp, kvt, km);
  k3_attn  <<<dim3(N_/64, 2, B_),      256, 0, stream>>>(qt, kvt, km, attn);
  k4_pe    <<<dim3(C_, B_),            256, 0, stream>>>(x, attn, pew, peb, out);
}